// Round 2
// baseline (429.221 us; speedup 1.0000x reference)
//
#include <hip/hip_runtime.h>
#include <hip/hip_bf16.h>
#include <stdint.h>

#define K_DIM 4096
#define M_DIM 8192
#define N_DIM 4096

typedef short bf16x8 __attribute__((ext_vector_type(8)));
typedef float f32x4  __attribute__((ext_vector_type(4)));

__device__ __forceinline__ uint16_t f2bf(float f) {
  uint32_t u = __float_as_uint(f);
  u += 0x7fffu + ((u >> 16) & 1u);   // round-to-nearest-even
  return (uint16_t)(u >> 16);
}

__device__ __forceinline__ float wval(float b0, float b1, float b2, float sg) {
  float mg = (b0 >= 0.f ? 0.5f : 0.f) + (b1 >= 0.f ? 0.25f : 0.f) + (b2 >= 0.f ? 0.125f : 0.f);
  return (sg >= 0.f) ? mg : -mg;
}

__device__ __forceinline__ void gload16(const void* g, void* l) {
  typedef __attribute__((address_space(1))) const uint32_t gu32;
  typedef __attribute__((address_space(3))) uint32_t lu32;
  __builtin_amdgcn_global_load_lds((gu32*)g, (lu32*)l, 16, 0, 0);
}

// ---------- Kernel 1: W^T (bf16) build + transpose + per-block sum/sumsq ----
__global__ __launch_bounds__(256) void build_wt(
    const float* __restrict__ mag, const float* __restrict__ sgn,
    uint16_t* __restrict__ wt, float* __restrict__ psum, float* __restrict__ psumsq)
{
  __shared__ float wl[64][65];
  __shared__ float parts[8];
  const int tid = threadIdx.x;
  const int lr = tid >> 4;   // 0..15
  const int lc = tid & 15;   // 0..15
  const int i0 = blockIdx.y * 64;   // input-dim (K) tile
  const int o0 = blockIdx.x * 64;   // output-dim (N) tile
  const float* m0 = mag;
  const float* m1 = mag + (size_t)K_DIM * N_DIM;
  const float* m2 = mag + 2 * (size_t)K_DIM * N_DIM;

  float s = 0.f, s2 = 0.f;
  #pragma unroll
  for (int rg = 0; rg < 4; ++rg) {
    int il = rg * 16 + lr;
    size_t base = (size_t)(i0 + il) * N_DIM + o0 + lc * 4;
    float4 a = *(const float4*)(m0 + base);
    float4 b = *(const float4*)(m1 + base);
    float4 c = *(const float4*)(m2 + base);
    float4 g = *(const float4*)(sgn + base);
    float w0 = wval(a.x, b.x, c.x, g.x);
    float w1 = wval(a.y, b.y, c.y, g.y);
    float w2 = wval(a.z, b.z, c.z, g.z);
    float w3 = wval(a.w, b.w, c.w, g.w);
    wl[il][lc * 4 + 0] = w0;
    wl[il][lc * 4 + 1] = w1;
    wl[il][lc * 4 + 2] = w2;
    wl[il][lc * 4 + 3] = w3;
    s  += w0 + w1 + w2 + w3;
    s2 += w0 * w0 + w1 * w1 + w2 * w2 + w3 * w3;
  }
  // deterministic per-block reduction (no float atomics -> replay-stable)
  #pragma unroll
  for (int off = 32; off > 0; off >>= 1) {
    s  += __shfl_down(s,  off);
    s2 += __shfl_down(s2, off);
  }
  if ((tid & 63) == 0) { parts[tid >> 6] = s; parts[4 + (tid >> 6)] = s2; }
  __syncthreads();
  if (tid == 0) {
    int bid = blockIdx.y * gridDim.x + blockIdx.x;
    psum[bid]   = parts[0] + parts[1] + parts[2] + parts[3];
    psumsq[bid] = parts[4] + parts[5] + parts[6] + parts[7];
  }
  // transposed coalesced write: Wt[o][i]
  #pragma unroll
  for (int rg = 0; rg < 4; ++rg) {
    int ol = rg * 16 + lr;
    int il = lc * 4;
    ushort4 v;
    v.x = f2bf(wl[il + 0][ol]);
    v.y = f2bf(wl[il + 1][ol]);
    v.z = f2bf(wl[il + 2][ol]);
    v.w = f2bf(wl[il + 3][ol]);
    *(ushort4*)(wt + (size_t)(o0 + ol) * K_DIM + i0 + il) = v;
  }
}

// ---------- Kernel 2: x f32 -> bf16 ----------
__global__ __launch_bounds__(256) void cvt_x(const float* __restrict__ x,
                                             uint16_t* __restrict__ xb, int n8)
{
  int idx = blockIdx.x * blockDim.x + threadIdx.x;
  int stride = gridDim.x * blockDim.x;
  for (; idx < n8; idx += stride) {
    float4 v0 = ((const float4*)x)[2 * idx];
    float4 v1 = ((const float4*)x)[2 * idx + 1];
    ushort4 r0, r1;
    r0.x = f2bf(v0.x); r0.y = f2bf(v0.y); r0.z = f2bf(v0.z); r0.w = f2bf(v0.w);
    r1.x = f2bf(v1.x); r1.y = f2bf(v1.y); r1.z = f2bf(v1.z); r1.w = f2bf(v1.w);
    ((ushort4*)xb)[2 * idx]     = r0;
    ((ushort4*)xb)[2 * idx + 1] = r1;
  }
}

// ---------- Kernel 3: alpha = std_target / (std(w) + eps) ----------
__global__ __launch_bounds__(256) void calc_alpha(const float* __restrict__ psum,
                                                  const float* __restrict__ psumsq,
                                                  float* __restrict__ alpha, int nparts)
{
  __shared__ float ls[256], lq[256];
  int tid = threadIdx.x;
  float s = 0.f, q = 0.f;
  for (int i = tid; i < nparts; i += 256) { s += psum[i]; q += psumsq[i]; }
  ls[tid] = s; lq[tid] = q;
  __syncthreads();
  for (int off = 128; off > 0; off >>= 1) {
    if (tid < off) { ls[tid] += ls[tid + off]; lq[tid] += lq[tid + off]; }
    __syncthreads();
  }
  if (tid == 0) {
    const float n = 16777216.f;
    float mean = ls[0] / n;
    float var  = lq[0] / n - mean * mean;
    var = var < 0.f ? 0.f : var;
    float stdv = sqrtf(var);
    alpha[0] = 0.022097086912079608f / (stdv + 1e-8f);  // sqrt(2/4096)/(std+eps)
  }
}

// ---------- Kernel 4: deep-pipelined 256x256 bf16 MFMA GEMM ----------
// BM=BN=256, BK=32, 8 waves (2m x 4n), wave C = 128x64 (8x4 frags 16x16).
// 4 rotating LDS K-tile buffers (4 x (A 16KB + B 16KB) = 128 KiB).
// Iter t: compute kt from buf[t&3]; prefetch kt+3 into buf[(t-1)&3]
// (retired last iter -> write-after-read safe with the single barrier).
// One s_waitcnt vmcnt(8) + one s_barrier per K-tile; never drain to 0.
// LDS swizzle for [256 rows][64B] tiles: cb ^= ((row&3)^((row>>2)&3))<<4
// (2 lanes/bank on ds_read_b128 = conflict-free); involution pre-applied to
// the global source so global_load_lds dest stays linear (rule 21).
#define BMT 256
#define BKT 32
#define NT  (K_DIM / BKT)

__global__ __launch_bounds__(512, 2) void gemm_bf16_dp(
    const uint16_t* __restrict__ xb, const uint16_t* __restrict__ wt,
    const float* __restrict__ alphap, float* __restrict__ out)
{
  __shared__ __align__(16) unsigned char sA[4][BMT * 64];
  __shared__ __align__(16) unsigned char sB[4][BMT * 64];

  const int tid  = threadIdx.x;
  const int lane = tid & 63;
  const int wv   = tid >> 6;        // 0..7
  const int wm   = wv >> 2;         // 0..1 -> 128-row half of C-rows
  const int wn   = wv & 3;          // 0..3 -> 64-col quarter of C-cols

  // XCD-aware swizzle: 512 blocks = 8 XCD regions of 8x8 blocks (2x4 region grid)
  const int bid = blockIdx.x;
  const int xcd = bid & 7;
  const int c   = bid >> 3;                  // 0..63
  const int bm  = (xcd >> 1) * 8 + (c >> 3); // 0..31
  const int bn  = (xcd & 1) * 8 + (c & 7);   // 0..15

  const size_t rowA0 = (size_t)bm * BMT;
  const size_t rowB0 = (size_t)bn * BMT;

  f32x4 acc[8][4] = {};

  // --- staging constants (global_load_lds, 16B/lane) ---
  // inst j covers rows j*128..j*128+127; thread -> row = j*128 + (tid>>2),
  // linear dest col-byte (tid&3)*16; source col pre-inverse-swizzled.
  const int srow   = tid >> 2;                                   // 0..127
  const int sswz   = ((srow & 3) ^ ((srow >> 2) & 3)) << 4;
  const int src_cb = ((tid & 3) << 4) ^ sswz;

  // --- fragment-read constants ---
  // row_l = base16 + (lane&15): swz(row_l) = (lane&3)^((lane>>2)&3)
  const int frag_cb = (((lane >> 4) << 4)) ^ ((((lane & 3) ^ ((lane >> 2) & 3))) << 4);
  const int arow = wm * 128 + (lane & 15);
  const int brow = wn * 64  + (lane & 15);

#define STAGE(gptr, grow0, sbuf, j, pk) do {                                        \
    const char* _g = (const char*)(gptr)                                            \
        + ((((grow0) + (j) * 128 + srow) * (size_t)K_DIM + (size_t)(pk)) << 1)      \
        + src_cb;                                                                   \
    gload16(_g, (sbuf) + (j) * 8192 + wv * 1024);                                   \
  } while (0)

  // prologue: stage K-tiles 0,1,2 into bufs 0,1,2 (12 loads in flight)
  #pragma unroll
  for (int p = 0; p < 3; ++p) {
    STAGE(xb, rowA0, sA[p], 0, p * BKT);
    STAGE(xb, rowA0, sA[p], 1, p * BKT);
    STAGE(wt, rowB0, sB[p], 0, p * BKT);
    STAGE(wt, rowB0, sB[p], 1, p * BKT);
  }

  for (int t = 0; t < NT; ++t) {
    // own kt loads landed (oldest beyond 8 = kt's 4), then all waves' visible
    asm volatile("s_waitcnt vmcnt(8)\n\ts_barrier" ::: "memory");

    const unsigned char* Ab = sA[t & 3];
    const unsigned char* Bb = sB[t & 3];
    const int  pb = (t + 3) & 3;
    const int  pk = (t + 3) * BKT;
    const bool pf = (t + 3) < NT;

    bf16x8 bfr[4];
    #pragma unroll
    for (int n = 0; n < 4; ++n)
      bfr[n] = *(const bf16x8*)(Bb + (size_t)(brow + n * 16) * 64 + frag_cb);

    #pragma unroll
    for (int q = 0; q < 4; ++q) {
      if (pf) {
        if      (q == 0) STAGE(xb, rowA0, sA[pb], 0, pk);
        else if (q == 1) STAGE(xb, rowA0, sA[pb], 1, pk);
        else if (q == 2) STAGE(wt, rowB0, sB[pb], 0, pk);
        else             STAGE(wt, rowB0, sB[pb], 1, pk);
      }
      bf16x8 a0 = *(const bf16x8*)(Ab + (size_t)(arow + (2 * q)     * 16) * 64 + frag_cb);
      bf16x8 a1 = *(const bf16x8*)(Ab + (size_t)(arow + (2 * q + 1) * 16) * 64 + frag_cb);
      __builtin_amdgcn_s_setprio(1);
      #pragma unroll
      for (int n = 0; n < 4; ++n) {
        acc[2 * q][n]     = __builtin_amdgcn_mfma_f32_16x16x32_bf16(a0, bfr[n], acc[2 * q][n],     0, 0, 0);
        acc[2 * q + 1][n] = __builtin_amdgcn_mfma_f32_16x16x32_bf16(a1, bfr[n], acc[2 * q + 1][n], 0, 0, 0);
      }
      __builtin_amdgcn_s_setprio(0);
    }
  }
#undef STAGE

  const float alpha = alphap[0];
  const int ccol  = bn * BMT + wn * 64 + (lane & 15);
  const int crow0 = bm * BMT + wm * 128 + ((lane >> 4) << 2);
  #pragma unroll
  for (int m = 0; m < 8; ++m)
    #pragma unroll
    for (int n = 0; n < 4; ++n)
      #pragma unroll
      for (int r = 0; r < 4; ++r)
        out[(size_t)(crow0 + m * 16 + r) * N_DIM + ccol + n * 16] = acc[m][n][r] * alpha;
}

extern "C" void kernel_launch(void* const* d_in, const int* in_sizes, int n_in,
                              void* d_out, int out_size, void* d_ws, size_t ws_size,
                              hipStream_t stream) {
  const float* x   = (const float*)d_in[0];
  const float* mag = (const float*)d_in[1];
  const float* sgn = (const float*)d_in[2];
  float* out = (float*)d_out;

  char* ws = (char*)d_ws;
  float* alpha    = (float*)ws;
  float* psum     = (float*)(ws + 256);
  float* psumsq   = (float*)(ws + 256 + 16384);
  uint16_t* wt    = (uint16_t*)(ws + 256 + 32768);
  uint16_t* xb    = (uint16_t*)(ws + 256 + 32768 + 33554432ull);
  size_t needed = 256 + 32768 + 33554432ull + 67108864ull;
  if (ws_size < needed) return;

  build_wt<<<dim3(64, 64), 256, 0, stream>>>(mag, sgn, wt, psum, psumsq);
  cvt_x<<<dim3(2048), 256, 0, stream>>>(x, xb, (M_DIM * K_DIM) / 8);
  calc_alpha<<<dim3(1), 256, 0, stream>>>(psum, psumsq, alpha, 4096);
  gemm_bf16_dp<<<dim3(512), 512, 0, stream>>>(xb, wt, alpha, out);
}

// Round 3
// 364.868 us; speedup vs baseline: 1.1764x; 1.1764x over previous
//
#include <hip/hip_runtime.h>
#include <hip/hip_bf16.h>
#include <stdint.h>

#define K_DIM 4096
#define M_DIM 8192
#define N_DIM 4096

typedef short bf16x8 __attribute__((ext_vector_type(8)));
typedef float f32x4  __attribute__((ext_vector_type(4)));

__device__ __forceinline__ uint16_t f2bf(float f) {
  uint32_t u = __float_as_uint(f);
  u += 0x7fffu + ((u >> 16) & 1u);   // round-to-nearest-even
  return (uint16_t)(u >> 16);
}

__device__ __forceinline__ float wval(float b0, float b1, float b2, float sg) {
  float mg = (b0 >= 0.f ? 0.5f : 0.f) + (b1 >= 0.f ? 0.25f : 0.f) + (b2 >= 0.f ? 0.125f : 0.f);
  return (sg >= 0.f) ? mg : -mg;
}

__device__ __forceinline__ void gload16(const void* g, void* l) {
  typedef __attribute__((address_space(1))) const uint32_t gu32;
  typedef __attribute__((address_space(3))) uint32_t lu32;
  __builtin_amdgcn_global_load_lds((gu32*)g, (lu32*)l, 16, 0, 0);
}

// ---------- Kernel 1: W^T (bf16) build + transpose + per-block sum/sumsq ----
__global__ __launch_bounds__(256) void build_wt(
    const float* __restrict__ mag, const float* __restrict__ sgn,
    uint16_t* __restrict__ wt, float* __restrict__ psum, float* __restrict__ psumsq)
{
  __shared__ float wl[64][65];
  __shared__ float parts[8];
  const int tid = threadIdx.x;
  const int lr = tid >> 4;   // 0..15
  const int lc = tid & 15;   // 0..15
  const int i0 = blockIdx.y * 64;   // input-dim (K) tile
  const int o0 = blockIdx.x * 64;   // output-dim (N) tile
  const float* m0 = mag;
  const float* m1 = mag + (size_t)K_DIM * N_DIM;
  const float* m2 = mag + 2 * (size_t)K_DIM * N_DIM;

  float s = 0.f, s2 = 0.f;
  #pragma unroll
  for (int rg = 0; rg < 4; ++rg) {
    int il = rg * 16 + lr;
    size_t base = (size_t)(i0 + il) * N_DIM + o0 + lc * 4;
    float4 a = *(const float4*)(m0 + base);
    float4 b = *(const float4*)(m1 + base);
    float4 c = *(const float4*)(m2 + base);
    float4 g = *(const float4*)(sgn + base);
    float w0 = wval(a.x, b.x, c.x, g.x);
    float w1 = wval(a.y, b.y, c.y, g.y);
    float w2 = wval(a.z, b.z, c.z, g.z);
    float w3 = wval(a.w, b.w, c.w, g.w);
    wl[il][lc * 4 + 0] = w0;
    wl[il][lc * 4 + 1] = w1;
    wl[il][lc * 4 + 2] = w2;
    wl[il][lc * 4 + 3] = w3;
    s  += w0 + w1 + w2 + w3;
    s2 += w0 * w0 + w1 * w1 + w2 * w2 + w3 * w3;
  }
  // deterministic per-block reduction (no float atomics -> replay-stable)
  #pragma unroll
  for (int off = 32; off > 0; off >>= 1) {
    s  += __shfl_down(s,  off);
    s2 += __shfl_down(s2, off);
  }
  if ((tid & 63) == 0) { parts[tid >> 6] = s; parts[4 + (tid >> 6)] = s2; }
  __syncthreads();
  if (tid == 0) {
    int bid = blockIdx.y * gridDim.x + blockIdx.x;
    psum[bid]   = parts[0] + parts[1] + parts[2] + parts[3];
    psumsq[bid] = parts[4] + parts[5] + parts[6] + parts[7];
  }
  // transposed coalesced write: Wt[o][i]
  #pragma unroll
  for (int rg = 0; rg < 4; ++rg) {
    int ol = rg * 16 + lr;
    int il = lc * 4;
    ushort4 v;
    v.x = f2bf(wl[il + 0][ol]);
    v.y = f2bf(wl[il + 1][ol]);
    v.z = f2bf(wl[il + 2][ol]);
    v.w = f2bf(wl[il + 3][ol]);
    *(ushort4*)(wt + (size_t)(o0 + ol) * K_DIM + i0 + il) = v;
  }
}

// ---------- Kernel 2: x f32 -> bf16 ----------
__global__ __launch_bounds__(256) void cvt_x(const float* __restrict__ x,
                                             uint16_t* __restrict__ xb, int n8)
{
  int idx = blockIdx.x * blockDim.x + threadIdx.x;
  int stride = gridDim.x * blockDim.x;
  for (; idx < n8; idx += stride) {
    float4 v0 = ((const float4*)x)[2 * idx];
    float4 v1 = ((const float4*)x)[2 * idx + 1];
    ushort4 r0, r1;
    r0.x = f2bf(v0.x); r0.y = f2bf(v0.y); r0.z = f2bf(v0.z); r0.w = f2bf(v0.w);
    r1.x = f2bf(v1.x); r1.y = f2bf(v1.y); r1.z = f2bf(v1.z); r1.w = f2bf(v1.w);
    ((ushort4*)xb)[2 * idx]     = r0;
    ((ushort4*)xb)[2 * idx + 1] = r1;
  }
}

// ---------- Kernel 3: alpha = std_target / (std(w) + eps) ----------
__global__ __launch_bounds__(256) void calc_alpha(const float* __restrict__ psum,
                                                  const float* __restrict__ psumsq,
                                                  float* __restrict__ alpha, int nparts)
{
  __shared__ float ls[256], lq[256];
  int tid = threadIdx.x;
  float s = 0.f, q = 0.f;
  for (int i = tid; i < nparts; i += 256) { s += psum[i]; q += psumsq[i]; }
  ls[tid] = s; lq[tid] = q;
  __syncthreads();
  for (int off = 128; off > 0; off >>= 1) {
    if (tid < off) { ls[tid] += ls[tid + off]; lq[tid] += lq[tid + off]; }
    __syncthreads();
  }
  if (tid == 0) {
    const float n = 16777216.f;
    float mean = ls[0] / n;
    float var  = lq[0] / n - mean * mean;
    var = var < 0.f ? 0.f : var;
    float stdv = sqrtf(var);
    alpha[0] = 0.022097086912079608f / (stdv + 1e-8f);  // sqrt(2/4096)/(std+eps)
  }
}

// ---------- Kernel 4: 256x256 deep-pipelined bf16 MFMA GEMM, BK=64 ----------
// 8 waves (2m x 4n), wave C = 128x64 = 8x4 frags of 16x16, K-step 64.
// LDS: 2 K-tile buffers x (A 32KB + B 32KB) = 128 KiB; rows are 128B so the
// round-1-verified zero-conflict swizzle applies: LDS[row][cb] holds
// global[row][cb ^ ((row&7)<<4)]  (linear gload_lds dest, pre-swizzled
// global source, swizzled ds_read — rule 21).
// Schedule per K-tile p: {vmcnt(0); barrier} (loads for p issued a FULL
// iteration ago -> no short-distance drain), then issue all 8 stage loads
// for tile p+1 into the buffer retired at this barrier, then 4 quadrant
// phases of 16 MFMA each with A/B frags register-cached across phases
// (24 ds_read_b128 per 64 wave-MFMA = 42.7 FLOP/LDS-byte).
#define NKT 64

__global__ __launch_bounds__(512, 2) void gemm_bf16_p2(
    const uint16_t* __restrict__ xb, const uint16_t* __restrict__ wt,
    const float* __restrict__ alphap, float* __restrict__ out)
{
  __shared__ __align__(16) unsigned char sA[2][256 * 128];
  __shared__ __align__(16) unsigned char sB[2][256 * 128];

  const int tid  = threadIdx.x;
  const int lane = tid & 63;
  const int wv   = tid >> 6;        // 0..7
  const int wm   = wv >> 2;         // 0..1 -> 128-row band
  const int wn   = wv & 3;          // 0..3 -> 64-col band

  // XCD-aware bijective swizzle: 512 blocks = 8 regions of 8x8
  const int bid = blockIdx.x;
  const int xcd = bid & 7;
  const int c   = bid >> 3;                  // 0..63
  const int bm  = (xcd >> 1) * 8 + (c >> 3); // 0..31
  const int bn  = (xcd & 1) * 8 + (c & 7);   // 0..15

  const size_t rowA0 = (size_t)bm * 256;
  const size_t rowB0 = (size_t)bn * 256;

  f32x4 acc[8][4] = {};

  const int l15  = lane & 15;
  // staging: lane covers row (.. + wv*8 + lane>>3), dest cb (lane&7)*16 (linear);
  // source col pre-swizzled by ((row&7)<<4), row&7 == (lane>>3)&7:
  const int src_x = ((lane & 7) ^ (lane >> 3)) << 4;
  // read-side swizzled k-column bytes (row&7 == lane&7 for all frag rows):
  const int cb0 = (((lane >> 4) << 4)) ^ ((lane & 7) << 4);        // kk=0
  const int cb1 = (64 | ((lane >> 4) << 4)) ^ ((lane & 7) << 4);   // kk=1

#define STAGEK(gp, grow0, dbuf, kb) do {                                          \
    _Pragma("unroll")                                                             \
    for (int hh = 0; hh < 4; ++hh) {                                              \
      int row = hh * 64 + wv * 8 + (lane >> 3);                                   \
      gload16((const char*)(gp) + ((((grow0) + row) * (size_t)K_DIM + (kb)) << 1) \
                  + src_x,                                                        \
              (dbuf) + hh * 8192 + wv * 1024);                                    \
    }                                                                             \
  } while (0)

  // prologue: stage K-tile 0 into buffer 0 (one short stall at iter 0 only)
  STAGEK(xb, rowA0, sA[0], 0);
  STAGEK(wt, rowB0, sB[0], 0);

  for (int p = 0; p < NKT; ++p) {
    // tile p's 8 loads were issued a full iteration ago -> near-zero wait
    asm volatile("s_waitcnt vmcnt(0)\n\ts_barrier" ::: "memory");
    const unsigned char* Ab = sA[p & 1];
    const unsigned char* Bb = sB[p & 1];

    if (p + 1 < NKT) {   // stage tile p+1 into the buffer retired at this barrier
      STAGEK(xb, rowA0, sA[(p + 1) & 1], (p + 1) * 64);
      STAGEK(wt, rowB0, sB[(p + 1) & 1], (p + 1) * 64);
    }

    bf16x8 Af[8], Bf0[4], Bf1[4];

    // ---- phase 0: quadrant (ah=0, bh=0); load Af(ah0) + Bf0 ----
    #pragma unroll
    for (int m = 0; m < 4; ++m) {
      const unsigned char* rp = Ab + (size_t)(wm * 128 + m * 16 + l15) * 128;
      Af[2 * m]     = *(const bf16x8*)(rp + cb0);
      Af[2 * m + 1] = *(const bf16x8*)(rp + cb1);
    }
    #pragma unroll
    for (int n = 0; n < 2; ++n) {
      const unsigned char* rp = Bb + (size_t)(wn * 64 + n * 16 + l15) * 128;
      Bf0[2 * n]     = *(const bf16x8*)(rp + cb0);
      Bf0[2 * n + 1] = *(const bf16x8*)(rp + cb1);
    }
    __builtin_amdgcn_s_setprio(1);
    #pragma unroll
    for (int m = 0; m < 4; ++m)
      #pragma unroll
      for (int n = 0; n < 2; ++n) {
        acc[m][n] = __builtin_amdgcn_mfma_f32_16x16x32_bf16(Af[2 * m],     Bf0[2 * n],     acc[m][n], 0, 0, 0);
        acc[m][n] = __builtin_amdgcn_mfma_f32_16x16x32_bf16(Af[2 * m + 1], Bf0[2 * n + 1], acc[m][n], 0, 0, 0);
      }
    __builtin_amdgcn_s_setprio(0);

    // ---- phase 1: quadrant (ah=0, bh=1); load Bf1, reuse Af ----
    #pragma unroll
    for (int n = 0; n < 2; ++n) {
      const unsigned char* rp = Bb + (size_t)(wn * 64 + 32 + n * 16 + l15) * 128;
      Bf1[2 * n]     = *(const bf16x8*)(rp + cb0);
      Bf1[2 * n + 1] = *(const bf16x8*)(rp + cb1);
    }
    __builtin_amdgcn_s_setprio(1);
    #pragma unroll
    for (int m = 0; m < 4; ++m)
      #pragma unroll
      for (int n = 0; n < 2; ++n) {
        acc[m][2 + n] = __builtin_amdgcn_mfma_f32_16x16x32_bf16(Af[2 * m],     Bf1[2 * n],     acc[m][2 + n], 0, 0, 0);
        acc[m][2 + n] = __builtin_amdgcn_mfma_f32_16x16x32_bf16(Af[2 * m + 1], Bf1[2 * n + 1], acc[m][2 + n], 0, 0, 0);
      }
    __builtin_amdgcn_s_setprio(0);

    // ---- phase 2: quadrant (ah=1, bh=0); reload Af(ah1), reuse Bf0 ----
    #pragma unroll
    for (int m = 0; m < 4; ++m) {
      const unsigned char* rp = Ab + (size_t)(wm * 128 + 64 + m * 16 + l15) * 128;
      Af[2 * m]     = *(const bf16x8*)(rp + cb0);
      Af[2 * m + 1] = *(const bf16x8*)(rp + cb1);
    }
    __builtin_amdgcn_s_setprio(1);
    #pragma unroll
    for (int m = 0; m < 4; ++m)
      #pragma unroll
      for (int n = 0; n < 2; ++n) {
        acc[4 + m][n] = __builtin_amdgcn_mfma_f32_16x16x32_bf16(Af[2 * m],     Bf0[2 * n],     acc[4 + m][n], 0, 0, 0);
        acc[4 + m][n] = __builtin_amdgcn_mfma_f32_16x16x32_bf16(Af[2 * m + 1], Bf0[2 * n + 1], acc[4 + m][n], 0, 0, 0);
      }
    __builtin_amdgcn_s_setprio(0);

    // ---- phase 3: quadrant (ah=1, bh=1); no loads ----
    __builtin_amdgcn_s_setprio(1);
    #pragma unroll
    for (int m = 0; m < 4; ++m)
      #pragma unroll
      for (int n = 0; n < 2; ++n) {
        acc[4 + m][2 + n] = __builtin_amdgcn_mfma_f32_16x16x32_bf16(Af[2 * m],     Bf1[2 * n],     acc[4 + m][2 + n], 0, 0, 0);
        acc[4 + m][2 + n] = __builtin_amdgcn_mfma_f32_16x16x32_bf16(Af[2 * m + 1], Bf1[2 * n + 1], acc[4 + m][2 + n], 0, 0, 0);
      }
    __builtin_amdgcn_s_setprio(0);
  }
#undef STAGEK

  const float alpha = alphap[0];
  const int ccol  = bn * 256 + wn * 64 + l15;
  const int crow0 = bm * 256 + wm * 128 + ((lane >> 4) << 2);
  #pragma unroll
  for (int am = 0; am < 8; ++am)
    #pragma unroll
    for (int an = 0; an < 4; ++an)
      #pragma unroll
      for (int r = 0; r < 4; ++r)
        out[(size_t)(crow0 + am * 16 + r) * N_DIM + ccol + an * 16] = acc[am][an][r] * alpha;
}

extern "C" void kernel_launch(void* const* d_in, const int* in_sizes, int n_in,
                              void* d_out, int out_size, void* d_ws, size_t ws_size,
                              hipStream_t stream) {
  const float* x   = (const float*)d_in[0];
  const float* mag = (const float*)d_in[1];
  const float* sgn = (const float*)d_in[2];
  float* out = (float*)d_out;

  char* ws = (char*)d_ws;
  float* alpha    = (float*)ws;
  float* psum     = (float*)(ws + 256);
  float* psumsq   = (float*)(ws + 256 + 16384);
  uint16_t* wt    = (uint16_t*)(ws + 256 + 32768);
  uint16_t* xb    = (uint16_t*)(ws + 256 + 32768 + 33554432ull);
  size_t needed = 256 + 32768 + 33554432ull + 67108864ull;
  if (ws_size < needed) return;

  build_wt<<<dim3(64, 64), 256, 0, stream>>>(mag, sgn, wt, psum, psumsq);
  cvt_x<<<dim3(2048), 256, 0, stream>>>(x, xb, (M_DIM * K_DIM) / 8);
  calc_alpha<<<dim3(1), 256, 0, stream>>>(psum, psumsq, alpha, 4096);
  gemm_bf16_p2<<<dim3(512), 512, 0, stream>>>(xb, wt, alpha, out);
}

// Round 4
// 334.504 us; speedup vs baseline: 1.2832x; 1.0908x over previous
//
#include <hip/hip_runtime.h>
#include <hip/hip_bf16.h>
#include <stdint.h>

#define K_DIM 4096
#define M_DIM 8192
#define N_DIM 4096

typedef short bf16x8 __attribute__((ext_vector_type(8)));
typedef float f32x4  __attribute__((ext_vector_type(4)));

__device__ __forceinline__ uint16_t f2bf(float f) {
  uint32_t u = __float_as_uint(f);
  u += 0x7fffu + ((u >> 16) & 1u);   // round-to-nearest-even
  return (uint16_t)(u >> 16);
}

__device__ __forceinline__ float wval(float b0, float b1, float b2, float sg) {
  float mg = (b0 >= 0.f ? 0.5f : 0.f) + (b1 >= 0.f ? 0.25f : 0.f) + (b2 >= 0.f ? 0.125f : 0.f);
  return (sg >= 0.f) ? mg : -mg;
}

__device__ __forceinline__ void gload16(const void* g, void* l) {
  typedef __attribute__((address_space(1))) const uint32_t gu32;
  typedef __attribute__((address_space(3))) uint32_t lu32;
  __builtin_amdgcn_global_load_lds((gu32*)g, (lu32*)l, 16, 0, 0);
}

// ---------- Kernel 1: W^T (bf16) build + transpose + per-block sum/sumsq ----
__global__ __launch_bounds__(256) void build_wt(
    const float* __restrict__ mag, const float* __restrict__ sgn,
    uint16_t* __restrict__ wt, float* __restrict__ psum, float* __restrict__ psumsq)
{
  __shared__ float wl[64][65];
  __shared__ float parts[8];
  const int tid = threadIdx.x;
  const int lr = tid >> 4;   // 0..15
  const int lc = tid & 15;   // 0..15
  const int i0 = blockIdx.y * 64;   // input-dim (K) tile
  const int o0 = blockIdx.x * 64;   // output-dim (N) tile
  const float* m0 = mag;
  const float* m1 = mag + (size_t)K_DIM * N_DIM;
  const float* m2 = mag + 2 * (size_t)K_DIM * N_DIM;

  float s = 0.f, s2 = 0.f;
  #pragma unroll
  for (int rg = 0; rg < 4; ++rg) {
    int il = rg * 16 + lr;
    size_t base = (size_t)(i0 + il) * N_DIM + o0 + lc * 4;
    float4 a = *(const float4*)(m0 + base);
    float4 b = *(const float4*)(m1 + base);
    float4 c = *(const float4*)(m2 + base);
    float4 g = *(const float4*)(sgn + base);
    float w0 = wval(a.x, b.x, c.x, g.x);
    float w1 = wval(a.y, b.y, c.y, g.y);
    float w2 = wval(a.z, b.z, c.z, g.z);
    float w3 = wval(a.w, b.w, c.w, g.w);
    wl[il][lc * 4 + 0] = w0;
    wl[il][lc * 4 + 1] = w1;
    wl[il][lc * 4 + 2] = w2;
    wl[il][lc * 4 + 3] = w3;
    s  += w0 + w1 + w2 + w3;
    s2 += w0 * w0 + w1 * w1 + w2 * w2 + w3 * w3;
  }
  // deterministic per-block reduction (no float atomics -> replay-stable)
  #pragma unroll
  for (int off = 32; off > 0; off >>= 1) {
    s  += __shfl_down(s,  off);
    s2 += __shfl_down(s2, off);
  }
  if ((tid & 63) == 0) { parts[tid >> 6] = s; parts[4 + (tid >> 6)] = s2; }
  __syncthreads();
  if (tid == 0) {
    int bid = blockIdx.y * gridDim.x + blockIdx.x;
    psum[bid]   = parts[0] + parts[1] + parts[2] + parts[3];
    psumsq[bid] = parts[4] + parts[5] + parts[6] + parts[7];
  }
  // transposed coalesced write: Wt[o][i]
  #pragma unroll
  for (int rg = 0; rg < 4; ++rg) {
    int ol = rg * 16 + lr;
    int il = lc * 4;
    ushort4 v;
    v.x = f2bf(wl[il + 0][ol]);
    v.y = f2bf(wl[il + 1][ol]);
    v.z = f2bf(wl[il + 2][ol]);
    v.w = f2bf(wl[il + 3][ol]);
    *(ushort4*)(wt + (size_t)(o0 + ol) * K_DIM + i0 + il) = v;
  }
}

// ---------- Kernel 2: x f32 -> bf16 ----------
__global__ __launch_bounds__(256) void cvt_x(const float* __restrict__ x,
                                             uint16_t* __restrict__ xb, int n8)
{
  int idx = blockIdx.x * blockDim.x + threadIdx.x;
  int stride = gridDim.x * blockDim.x;
  for (; idx < n8; idx += stride) {
    float4 v0 = ((const float4*)x)[2 * idx];
    float4 v1 = ((const float4*)x)[2 * idx + 1];
    ushort4 r0, r1;
    r0.x = f2bf(v0.x); r0.y = f2bf(v0.y); r0.z = f2bf(v0.z); r0.w = f2bf(v0.w);
    r1.x = f2bf(v1.x); r1.y = f2bf(v1.y); r1.z = f2bf(v1.z); r1.w = f2bf(v1.w);
    ((ushort4*)xb)[2 * idx]     = r0;
    ((ushort4*)xb)[2 * idx + 1] = r1;
  }
}

// ---------- Kernel 3: alpha = std_target / (std(w) + eps) ----------
__global__ __launch_bounds__(256) void calc_alpha(const float* __restrict__ psum,
                                                  const float* __restrict__ psumsq,
                                                  float* __restrict__ alpha, int nparts)
{
  __shared__ float ls[256], lq[256];
  int tid = threadIdx.x;
  float s = 0.f, q = 0.f;
  for (int i = tid; i < nparts; i += 256) { s += psum[i]; q += psumsq[i]; }
  ls[tid] = s; lq[tid] = q;
  __syncthreads();
  for (int off = 128; off > 0; off >>= 1) {
    if (tid < off) { ls[tid] += ls[tid + off]; lq[tid] += lq[tid + off]; }
    __syncthreads();
  }
  if (tid == 0) {
    const float n = 16777216.f;
    float mean = ls[0] / n;
    float var  = lq[0] / n - mean * mean;
    var = var < 0.f ? 0.f : var;
    float stdv = sqrtf(var);
    alpha[0] = 0.022097086912079608f / (stdv + 1e-8f);  // sqrt(2/4096)/(std+eps)
  }
}

// ---------- Kernel 4: 256x256 8-phase bf16 MFMA GEMM (m201-style) ----------
// 8 waves (2m x 4n), wave C = 128x64 (8x4 frags 16x16), BK=64, 2 K-tiles/iter.
// LDS 128 KiB: per matrix 2 tile-buffers of [256 rows][128 B], rows REMAPPED so
// each half-tile is a contiguous 16 KB region:
//   A LDS row = mh*128 + wm*64 + i   (tile row = wm*128 + mh*64 + i)
//   B LDS row = bh*128 + wn*32 + j   (tile row = wn*64 + bh*32 + j)
// Zero-conflict swizzle (round-1/3 verified): LDS[row][cb] = global[.. cb^((row&7)<<4)]
// (linear gload_lds dest, pre-swizzled global source, swizzled ds_read).
// Per phase: {ds_reads; stage 1 half-tile; [vmcnt(4) at p3/p7]; barrier;
//             lgkmcnt(0)+sched_barrier; setprio(1); 16 MFMA; setprio(0); barrier}
// Stage targets the half-slot last read >=2 barriers earlier (progressive
// overwrite) giving 5-6 phase load flight; vmcnt(4) keeps 2 half-tiles in
// flight across the barrier (never drains to 0 mid-loop).
__global__ __launch_bounds__(512, 2) void gemm_bf16_8p(
    const uint16_t* __restrict__ xb, const uint16_t* __restrict__ wt,
    const float* __restrict__ alphap, float* __restrict__ out)
{
  __shared__ __align__(16) unsigned char sA[2][256 * 128];
  __shared__ __align__(16) unsigned char sB[2][256 * 128];

  const int tid  = threadIdx.x;
  const int lane = tid & 63;
  const int wv   = tid >> 6;        // 0..7
  const int wm   = wv >> 2;         // 0..1
  const int wn   = wv & 3;          // 0..3

  // XCD-aware bijective swizzle: 512 blocks = 8 regions of 8x8
  const int bid = blockIdx.x;
  const int xcd = bid & 7;
  const int c   = bid >> 3;                  // 0..63
  const int bm  = (xcd >> 1) * 8 + (c >> 3); // 0..31
  const int bn  = (xcd & 1) * 8 + (c & 7);   // 0..15

  const size_t rowA0 = (size_t)bm * 256;
  const size_t rowB0 = (size_t)bn * 256;

  f32x4 acc[8][4] = {};

  const int l15   = lane & 15;
  const int src_x = ((lane & 7) ^ (lane >> 3)) << 4;            // staging source pre-swizzle
  const int cb0   = (((lane >> 4) << 4)) ^ ((lane & 7) << 4);   // kk=0 read col-bytes
  const int cb1   = (64 | ((lane >> 4) << 4)) ^ ((lane & 7) << 4);

// stage one 64-row chunk (8 KB): wave wv covers LDS rows r0+wv*8..+7
#define STA(cc, mh, h, kt)                                                          \
  gload16((const char*)xb + (((rowA0 + (h) * 128 + (mh) * 64 + wv * 8 + (lane >> 3)) \
              * (size_t)K_DIM + (size_t)(kt) * 64) << 1) + src_x,                   \
          sA[cc] + ((mh) * 128 + (h) * 64 + wv * 8) * 128)
#define STB(cc, bh, h, kt)                                                          \
  gload16((const char*)wt + (((rowB0 + (2 * (h) + (wv >> 2)) * 64 + (bh) * 32       \
              + (wv & 3) * 8 + (lane >> 3)) * (size_t)K_DIM + (size_t)(kt) * 64) << 1) + src_x, \
          sB[cc] + ((bh) * 128 + (h) * 64 + wv * 8) * 128)
#define STAGE_A(cc, mh, kt) do { STA(cc, mh, 0, kt); STA(cc, mh, 1, kt); } while (0)
#define STAGE_B(cc, bh, kt) do { STB(cc, bh, 0, kt); STB(cc, bh, 1, kt); } while (0)

#define LDA8(mh) do { _Pragma("unroll")                                             \
  for (int m = 0; m < 4; ++m) {                                                     \
    const unsigned char* rp = Ab + (size_t)((mh) * 128 + wm * 64 + m * 16 + l15) * 128; \
    Afr[2 * m]     = *(const bf16x8*)(rp + cb0);                                    \
    Afr[2 * m + 1] = *(const bf16x8*)(rp + cb1); } } while (0)
#define LDB4(bh, Bfr) do { _Pragma("unroll")                                        \
  for (int n = 0; n < 2; ++n) {                                                     \
    const unsigned char* rp = Bb + (size_t)((bh) * 128 + wn * 32 + n * 16 + l15) * 128; \
    Bfr[2 * n]     = *(const bf16x8*)(rp + cb0);                                    \
    Bfr[2 * n + 1] = *(const bf16x8*)(rp + cb1); } } while (0)

#define MMQ(mh, bh, Bfr) do {                                                       \
  __builtin_amdgcn_s_setprio(1);                                                    \
  _Pragma("unroll") for (int m = 0; m < 4; ++m)                                     \
    _Pragma("unroll") for (int n = 0; n < 2; ++n) {                                 \
      acc[(mh)*4+m][(bh)*2+n] = __builtin_amdgcn_mfma_f32_16x16x32_bf16(            \
          Afr[2*m],   Bfr[2*n],   acc[(mh)*4+m][(bh)*2+n], 0, 0, 0);                \
      acc[(mh)*4+m][(bh)*2+n] = __builtin_amdgcn_mfma_f32_16x16x32_bf16(            \
          Afr[2*m+1], Bfr[2*n+1], acc[(mh)*4+m][(bh)*2+n], 0, 0, 0); }              \
  __builtin_amdgcn_s_setprio(0); } while (0)

#define WAITV(N) asm volatile("s_waitcnt vmcnt(" #N ")" ::: "memory")
#define BAR      asm volatile("s_barrier" ::: "memory")
#define LGKM0    do { asm volatile("s_waitcnt lgkmcnt(0)" ::: "memory");            \
                      __builtin_amdgcn_sched_barrier(0); } while (0)

  bf16x8 Afr[8], Bfr0[4], Bfr1[4];
  const unsigned char* Ab;
  const unsigned char* Bb;

  // prologue: tile0 all 4 halves + tile1 {A-h0, B-h0}; drain tile0 (keep 2 halves)
  STAGE_A(0, 0, 0); STAGE_B(0, 0, 0); STAGE_B(0, 1, 0); STAGE_A(0, 1, 0);
  STAGE_A(1, 0, 1); STAGE_B(1, 0, 1);
  WAITV(4); BAR;

  #pragma unroll 1
  for (int t = 0; t < 31; ++t) {
    // ===== phases 0-3: compute tile u=2t from buf0 =====
    Ab = sA[0]; Bb = sB[0];
    // p0
    LDA8(0); LDB4(0, Bfr0);
    STAGE_B(1, 1, 2 * t + 1);
    BAR; LGKM0; MMQ(0, 0, Bfr0); BAR;
    // p1
    LDB4(1, Bfr1);
    STAGE_A(1, 1, 2 * t + 1);
    BAR; LGKM0; MMQ(0, 1, Bfr1); BAR;
    // p2
    LDA8(1);
    STAGE_A(0, 0, 2 * t + 2);
    BAR; LGKM0; MMQ(1, 0, Bfr0); BAR;
    // p3 (vmcnt before closing barrier covers phases 4-7's reads of tile 2t+1)
    STAGE_B(0, 0, 2 * t + 2);
    BAR; LGKM0; MMQ(1, 1, Bfr1);
    WAITV(4); BAR;

    // ===== phases 4-7: compute tile v=2t+1 from buf1 =====
    Ab = sA[1]; Bb = sB[1];
    // p4
    LDA8(0); LDB4(0, Bfr0);
    STAGE_B(0, 1, 2 * t + 2);
    BAR; LGKM0; MMQ(0, 0, Bfr0); BAR;
    // p5
    LDB4(1, Bfr1);
    STAGE_A(0, 1, 2 * t + 2);
    BAR; LGKM0; MMQ(0, 1, Bfr1); BAR;
    // p6
    LDA8(1);
    STAGE_A(1, 0, 2 * t + 3);
    BAR; LGKM0; MMQ(1, 0, Bfr0); BAR;
    // p7 (vmcnt covers next iteration's phases 0-3 reads of tile 2t+2)
    STAGE_B(1, 0, 2 * t + 3);
    BAR; LGKM0; MMQ(1, 1, Bfr1);
    WAITV(4); BAR;
  }

  // ===== peeled t=31: tiles 62 (buf0) / 63 (buf1); no stages past p1 =====
  Ab = sA[0]; Bb = sB[0];
  LDA8(0); LDB4(0, Bfr0);
  STAGE_B(1, 1, 63);
  BAR; LGKM0; MMQ(0, 0, Bfr0); BAR;
  LDB4(1, Bfr1);
  STAGE_A(1, 1, 63);
  BAR; LGKM0; MMQ(0, 1, Bfr1); BAR;
  LDA8(1);
  BAR; LGKM0; MMQ(1, 0, Bfr0); BAR;
  BAR; LGKM0; MMQ(1, 1, Bfr1);
  WAITV(0); BAR;
  Ab = sA[1]; Bb = sB[1];
  LDA8(0); LDB4(0, Bfr0);
  BAR; LGKM0; MMQ(0, 0, Bfr0); BAR;
  LDB4(1, Bfr1);
  BAR; LGKM0; MMQ(0, 1, Bfr1); BAR;
  LDA8(1);
  BAR; LGKM0; MMQ(1, 0, Bfr0); BAR;
  BAR; LGKM0; MMQ(1, 1, Bfr1); BAR;

#undef STA
#undef STB
#undef STAGE_A
#undef STAGE_B
#undef LDA8
#undef LDB4
#undef MMQ
#undef WAITV
#undef BAR
#undef LGKM0

  const float alpha = alphap[0];
  const int ccol  = bn * 256 + wn * 64 + l15;
  const int crow0 = bm * 256 + wm * 128 + ((lane >> 4) << 2);
  #pragma unroll
  for (int am = 0; am < 8; ++am)
    #pragma unroll
    for (int an = 0; an < 4; ++an)
      #pragma unroll
      for (int r = 0; r < 4; ++r)
        out[(size_t)(crow0 + am * 16 + r) * N_DIM + ccol + an * 16] = acc[am][an][r] * alpha;
}

extern "C" void kernel_launch(void* const* d_in, const int* in_sizes, int n_in,
                              void* d_out, int out_size, void* d_ws, size_t ws_size,
                              hipStream_t stream) {
  const float* x   = (const float*)d_in[0];
  const float* mag = (const float*)d_in[1];
  const float* sgn = (const float*)d_in[2];
  float* out = (float*)d_out;

  char* ws = (char*)d_ws;
  float* alpha    = (float*)ws;
  float* psum     = (float*)(ws + 256);
  float* psumsq   = (float*)(ws + 256 + 16384);
  uint16_t* wt    = (uint16_t*)(ws + 256 + 32768);
  uint16_t* xb    = (uint16_t*)(ws + 256 + 32768 + 33554432ull);
  size_t needed = 256 + 32768 + 33554432ull + 67108864ull;
  if (ws_size < needed) return;

  build_wt<<<dim3(64, 64), 256, 0, stream>>>(mag, sgn, wt, psum, psumsq);
  cvt_x<<<dim3(2048), 256, 0, stream>>>(x, xb, (M_DIM * K_DIM) / 8);
  calc_alpha<<<dim3(1), 256, 0, stream>>>(psum, psumsq, alpha, 4096);
  gemm_bf16_8p<<<dim3(512), 512, 0, stream>>>(xb, wt, alpha, out);
}